// Round 5
// baseline (573.677 us; speedup 1.0000x reference)
//
#include <hip/hip_runtime.h>
#include <hip/hip_bf16.h>
#include <hip/hip_cooperative_groups.h>

namespace cg = cooperative_groups;

#define N_NODES 50000
#define N_EDGES 800000
// IN_F = 64, D_ATT = 64, HEADS = 8, D_HEAD = 8
// outputs: attention [E,8] | v [N,64] | prods [E,8]  (all fp32)

#define FUSED_THREADS (1024 * 256)   // 1024 blocks x 256 thr; 4 blk/CU at VGPR<=128

typedef __attribute__((ext_vector_type(4))) unsigned int uint4v;

static __device__ __forceinline__ float bfu_lo(unsigned int u) {
    union { unsigned int u; float f; } v; v.u = u << 16; return v.f;
}
static __device__ __forceinline__ float bfu_hi(unsigned int u) {
    union { unsigned int u; float f; } v; v.u = u & 0xffff0000u; return v.f;
}
static __device__ __forceinline__ unsigned short f2bf(float f) {
    union { float f; unsigned int u; } v; v.f = f;
    v.u += 0x7fffu + ((v.u >> 16) & 1u);  // RNE
    return (unsigned short)(v.u >> 16);
}

// ---------------------------------------------------------------------------
// Kernel 1: fused Q/K/V projection (single x staging; m-inner loop).
// R2 lesson: keep live register state small & chunked — per m-chunk only
// 16 W values live (48 accs + 16 w + addressing ~ 70 VGPR, budget 128).
// Q/K stored d-major bf16 (halves edge gather); V fp32 (output), NT store.
// ---------------------------------------------------------------------------
__global__ __launch_bounds__(256, 2)
void proj_qkv(const float* __restrict__ x,
              const float* __restrict__ Wq, const float* __restrict__ bq,
              const float* __restrict__ Wk, const float* __restrict__ bk,
              const float* __restrict__ Wv, const float* __restrict__ bv,
              unsigned short* __restrict__ Qb, unsigned short* __restrict__ Kb,
              float* __restrict__ V)
{
    __shared__ float xs[64 * 64];  // 16 KB
    const int tid  = threadIdx.x;
    const int c    = tid & 63;      // output column 0..63
    const int w    = tid >> 6;      // wave id 0..3
    const int row0 = blockIdx.x * 64;
    const int nrows = min(64, N_NODES - row0);

    // stage x tile once (coalesced float4)
    {
        const float4* xg  = (const float4*)(x + (size_t)row0 * 64);
        float4*       xs4 = (float4*)xs;
        const int nf4 = nrows * 16;
        for (int i = tid; i < nf4; i += 256) xs4[i] = xg[i];
    }
    __syncthreads();

    const float* Ws[3] = {Wq, Wk, Wv};
    const float* bs[3] = {bq, bk, bv};
    const int r0 = w * 16;
    // d-major permutation for Q/K rows (within the 128B row segment)
    const int ocqk = (c & 7) * 8 + (c >> 3);

    float acc[3][16];
#pragma unroll
    for (int m = 0; m < 3; ++m) {
        const float bc = bs[m][c];
#pragma unroll
        for (int i = 0; i < 16; ++i) acc[m][i] = bc;
    }

    for (int jc = 0; jc < 4; ++jc) {
#pragma unroll
        for (int m = 0; m < 3; ++m) {
            float wr[16];  // only 16 W values live at a time (L1-resident)
#pragma unroll
            for (int j = 0; j < 16; ++j) wr[j] = Ws[m][(jc * 16 + j) * 64 + c];
#pragma unroll
            for (int i = 0; i < 16; ++i) {
                const float4* xr = (const float4*)(xs + (r0 + i) * 64 + jc * 16);
#pragma unroll
                for (int j4 = 0; j4 < 4; ++j4) {
                    const float4 xv = xr[j4];  // wave-uniform broadcast
                    acc[m][i] += xv.x * wr[4 * j4 + 0];
                    acc[m][i] += xv.y * wr[4 * j4 + 1];
                    acc[m][i] += xv.z * wr[4 * j4 + 2];
                    acc[m][i] += xv.w * wr[4 * j4 + 3];
                }
            }
        }
    }

#pragma unroll
    for (int i = 0; i < 16; ++i) {
        const int r = r0 + i;
        if (r < nrows) {
            const size_t o = (size_t)(row0 + r) * 64;
            Qb[o + ocqk] = f2bf(acc[0][i]);
            Kb[o + ocqk] = f2bf(acc[1][i]);
            __builtin_nontemporal_store(acc[2][i], V + o + c);
        }
    }
}

// ---------------------------------------------------------------------------
// Kernel 2 (cooperative): zero ssum -> logits+exp+atomic segment-sum ->
// grid.sync -> normalize. Coherence across non-coherent per-XCD L2s:
//  - ssum touched ONLY via agent-scope atomics (store/add/load, memory-side)
//  - prods[gid] written and re-read by the SAME thread (own-L2 hit is safe)
// Softmax max-shift skipped: |p| <= ~8, exp() safe in fp32; ratio identical.
// ---------------------------------------------------------------------------
__global__ __launch_bounds__(256, 4)
void edge_fused(const unsigned short* __restrict__ Qb,
                const unsigned short* __restrict__ Kb,
                const int* __restrict__ edge,
                float* __restrict__ prods, float* __restrict__ att,
                float* __restrict__ ssum)
{
    const int tid0 = blockIdx.x * 256 + threadIdx.x;

    // phase 0: zero ssum (agent-scope stores bypass the local L2)
    for (int i = tid0; i < N_NODES * 8; i += FUSED_THREADS)
        __hip_atomic_store(ssum + i, 0.f, __ATOMIC_RELAXED,
                           __HIP_MEMORY_SCOPE_AGENT);
    __threadfence();
    cg::this_grid().sync();

    // phase 1: logits + exp + segment-sum
    for (int gid = tid0; gid < N_EDGES * 8; gid += FUSED_THREADS) {
        const int e = gid >> 3;
        const int d = gid & 7;
        const int e0 = edge[e];            // source node (q)
        const int e1 = edge[N_EDGES + e];  // destination node (k, segment id)

        const uint4v qv = *(const uint4v*)(Qb + (size_t)e0 * 64 + d * 8);
        const uint4v kv = *(const uint4v*)(Kb + (size_t)e1 * 64 + d * 8);
        float s = 0.f;
#pragma unroll
        for (int i = 0; i < 4; ++i) {
            s += bfu_lo(qv[i]) * bfu_lo(kv[i]);
            s += bfu_hi(qv[i]) * bfu_hi(kv[i]);
        }
        const float p = s * 0.35355339059327373f;  // 1/sqrt(8)
        prods[gid] = p;                             // plain store: re-read by
                                                    // same thread in phase 2
        atomicAdd(ssum + (size_t)e1 * 8 + d, __expf(p));
    }
    __threadfence();
    cg::this_grid().sync();

    // phase 2: normalize
    for (int gid = tid0; gid < N_EDGES * 8; gid += FUSED_THREADS) {
        const int e = gid >> 3;
        const int d = gid & 7;
        const int e1 = edge[N_EDGES + e];
        const float p = prods[gid];  // own-L2 hit (same thread wrote it)
        const float s = __hip_atomic_load(ssum + (size_t)e1 * 8 + d,
                                          __ATOMIC_RELAXED,
                                          __HIP_MEMORY_SCOPE_AGENT);
        __builtin_nontemporal_store(__expf(p) / (s + 1e-16f), att + gid);
    }
}

extern "C" void kernel_launch(void* const* d_in, const int* in_sizes, int n_in,
                              void* d_out, int out_size, void* d_ws, size_t ws_size,
                              hipStream_t stream)
{
    const float* x    = (const float*)d_in[0];
    const float* Wq   = (const float*)d_in[1];
    const float* bq   = (const float*)d_in[2];
    const float* Wk   = (const float*)d_in[3];
    const float* bk   = (const float*)d_in[4];
    const float* Wv   = (const float*)d_in[5];
    const float* bv   = (const float*)d_in[6];
    const int*   edge = (const int*)d_in[7];

    float* out   = (float*)d_out;
    float* att   = out;                      // 6,400,000 floats
    float* V     = out + 6400000;            // 3,200,000 floats
    float* prods = out + 9600000;            // 6,400,000 floats

    unsigned short* Qb = (unsigned short*)d_ws;      // 3.2M ushort (d-major bf16)
    unsigned short* Kb = Qb + 3200000;               // 3.2M ushort
    float*          ssum = (float*)(Kb + 3200000);   // 400,000 floats

    proj_qkv<<<(N_NODES + 63) / 64, 256, 0, stream>>>(x, Wq, bq, Wk, bk,
                                                      Wv, bv, Qb, Kb, V);

    void* args[] = {(void*)&Qb, (void*)&Kb, (void*)&edge,
                    (void*)&prods, (void*)&att, (void*)&ssum};
    hipLaunchCooperativeKernel((void*)edge_fused, dim3(1024), dim3(256),
                               args, 0, stream);
}

// Round 6
// 175.964 us; speedup vs baseline: 3.2602x; 3.2602x over previous
//
#include <hip/hip_runtime.h>
#include <hip/hip_bf16.h>

#define N_NODES 50000
#define N_EDGES 800000
// IN_F = 64, D_ATT = 64, HEADS = 8, D_HEAD = 8
// outputs: attention [E,8] | v [N,64] | prods [E,8]  (all fp32)

typedef __attribute__((ext_vector_type(4))) unsigned int uint4v;

static __device__ __forceinline__ float bfu_lo(unsigned int u) {
    union { unsigned int u; float f; } v; v.u = u << 16; return v.f;
}
static __device__ __forceinline__ float bfu_hi(unsigned int u) {
    union { unsigned int u; float f; } v; v.u = u & 0xffff0000u; return v.f;
}
static __device__ __forceinline__ unsigned short f2bf(float f) {
    union { float f; unsigned int u; } v; v.f = f;
    v.u += 0x7fffu + ((v.u >> 16) & 1u);  // RNE
    return (unsigned short)(v.u >> 16);
}

// ---------------------------------------------------------------------------
// Kernel 1: fused Q/K/V projection + ssum zeroing.
// R5 lesson: keep the massive-grid multi-kernel structure (cooperative
// grid-stride destroyed gather MLP: 444 us). R2 lesson: keep live register
// arrays small (K-chunk = 8 -> ~64 live VGPR, no spill).
// x tile (32 rows) staged once in LDS; each float4 read feeds all 3 W's
// (R4 read it 3x -> LDS-issue bound; now FMA-bound).
// Q/K stored d-major bf16 (halves edge gather); V fp32 (output).
// ssum zeroing folded here: kernel-end writeback makes it visible to the
// edge kernel's memory-side atomics (no extra memset dispatch).
// ---------------------------------------------------------------------------
__global__ __launch_bounds__(256, 2)
void proj_qkv(const float* __restrict__ x,
              const float* __restrict__ Wq, const float* __restrict__ bq,
              const float* __restrict__ Wk, const float* __restrict__ bk,
              const float* __restrict__ Wv, const float* __restrict__ bv,
              unsigned short* __restrict__ Qb, unsigned short* __restrict__ Kb,
              float* __restrict__ V, float* __restrict__ ssum)
{
    __shared__ float xs[32 * 64];  // 8 KB
    const int tid  = threadIdx.x;
    const int c    = tid & 63;      // output column 0..63
    const int w    = tid >> 6;      // wave id 0..3
    const int row0 = blockIdx.x * 32;
    const int nrows = min(32, N_NODES - row0);

    // ssum zeroing: one element per thread (grid covers 400128 >= 400000)
    {
        const int z = blockIdx.x * 256 + tid;
        if (z < N_NODES * 8) ssum[z] = 0.f;
    }

    // stage x tile once (coalesced float4)
    {
        const float4* xg  = (const float4*)(x + (size_t)row0 * 64);
        float4*       xs4 = (float4*)xs;
        const int nf4 = nrows * 16;
        for (int i = tid; i < nf4; i += 256) xs4[i] = xg[i];
    }
    __syncthreads();

    const int r0 = w * 8;  // this wave's 8 rows

    float accq[8], acck[8], accv[8];
    {
        const float bqc = bq[c], bkc = bk[c], bvc = bv[c];
#pragma unroll
        for (int i = 0; i < 8; ++i) { accq[i] = bqc; acck[i] = bkc; accv[i] = bvc; }
    }

    for (int jc = 0; jc < 8; ++jc) {  // K-dim in chunks of 8
        float wq[8], wk[8], wv[8];    // 24 live W values (L2-resident re-reads)
#pragma unroll
        for (int j = 0; j < 8; ++j) {
            const int row = (jc * 8 + j) * 64 + c;
            wq[j] = Wq[row]; wk[j] = Wk[row]; wv[j] = Wv[row];
        }
#pragma unroll
        for (int i = 0; i < 8; ++i) {
            const float4* xr = (const float4*)(xs + (r0 + i) * 64 + jc * 8);
            const float4 xv0 = xr[0], xv1 = xr[1];  // wave-uniform broadcast
            accq[i] += xv0.x * wq[0] + xv0.y * wq[1] + xv0.z * wq[2] + xv0.w * wq[3]
                     + xv1.x * wq[4] + xv1.y * wq[5] + xv1.z * wq[6] + xv1.w * wq[7];
            acck[i] += xv0.x * wk[0] + xv0.y * wk[1] + xv0.z * wk[2] + xv0.w * wk[3]
                     + xv1.x * wk[4] + xv1.y * wk[5] + xv1.z * wk[6] + xv1.w * wk[7];
            accv[i] += xv0.x * wv[0] + xv0.y * wv[1] + xv0.z * wv[2] + xv0.w * wv[3]
                     + xv1.x * wv[4] + xv1.y * wv[5] + xv1.z * wv[6] + xv1.w * wv[7];
        }
    }

    // d-major permutation for Q/K (within the 128B row segment) -> coalesced
    const int ocqk = (c & 7) * 8 + (c >> 3);
#pragma unroll
    for (int i = 0; i < 8; ++i) {
        const int r = r0 + i;
        if (r < nrows) {
            const size_t o = (size_t)(row0 + r) * 64;
            Qb[o + ocqk] = f2bf(accq[i]);
            Kb[o + ocqk] = f2bf(acck[i]);
            __builtin_nontemporal_store(accv[i], V + o + c);
        }
    }
}

// ---------------------------------------------------------------------------
// Kernel 2: per-(edge,d) logits + exp + segment-sum via atomics.
// One item per thread, 25000 blocks — oversubscription IS the latency hiding
// (R5 lesson). Qb/Kb d-major bf16: 8 head-summands = one 16 B load.
// Softmax max-shift skipped: |p| <= ~8, exp() safe in fp32; ratio identical.
// ---------------------------------------------------------------------------
__global__ __launch_bounds__(256)
void edge_kernel(const unsigned short* __restrict__ Qb,
                 const unsigned short* __restrict__ Kb,
                 const int* __restrict__ edge,
                 float* __restrict__ prods, float* __restrict__ ssum)
{
    const int gid = blockIdx.x * 256 + threadIdx.x;
    if (gid >= N_EDGES * 8) return;
    const int e = gid >> 3;
    const int d = gid & 7;
    const int e0 = edge[e];            // source node (q)
    const int e1 = edge[N_EDGES + e];  // destination node (k, segment id)

    const uint4v qv = *(const uint4v*)(Qb + (size_t)e0 * 64 + d * 8);
    const uint4v kv = *(const uint4v*)(Kb + (size_t)e1 * 64 + d * 8);
    float s = 0.f;
#pragma unroll
    for (int i = 0; i < 4; ++i) {
        s += bfu_lo(qv[i]) * bfu_lo(kv[i]);
        s += bfu_hi(qv[i]) * bfu_hi(kv[i]);
    }

    const float p = s * 0.35355339059327373f;  // 1/sqrt(8)
    prods[gid] = p;
    atomicAdd(ssum + (size_t)e1 * 8 + d, __expf(p));
}

// ---------------------------------------------------------------------------
// Kernel 3: attention = exp(prods) / segment-sum (exp recomputed — cheaper
// than a 25.6 MB round-trip of unnormalized values).
// ---------------------------------------------------------------------------
__global__ __launch_bounds__(256)
void norm_kernel(const int* __restrict__ edge,
                 const float* __restrict__ prods,
                 const float* __restrict__ ssum, float* __restrict__ att)
{
    const int gid = blockIdx.x * 256 + threadIdx.x;
    if (gid >= N_EDGES * 8) return;
    const int e = gid >> 3;
    const int d = gid & 7;
    const int e1 = edge[N_EDGES + e];
    const float ex = __expf(prods[gid]);
    __builtin_nontemporal_store(ex / (ssum[(size_t)e1 * 8 + d] + 1e-16f),
                                att + gid);
}

extern "C" void kernel_launch(void* const* d_in, const int* in_sizes, int n_in,
                              void* d_out, int out_size, void* d_ws, size_t ws_size,
                              hipStream_t stream)
{
    const float* x    = (const float*)d_in[0];
    const float* Wq   = (const float*)d_in[1];
    const float* bq   = (const float*)d_in[2];
    const float* Wk   = (const float*)d_in[3];
    const float* bk   = (const float*)d_in[4];
    const float* Wv   = (const float*)d_in[5];
    const float* bv   = (const float*)d_in[6];
    const int*   edge = (const int*)d_in[7];

    float* out   = (float*)d_out;
    float* att   = out;                      // 6,400,000 floats
    float* V     = out + 6400000;            // 3,200,000 floats
    float* prods = out + 9600000;            // 6,400,000 floats

    unsigned short* Qb = (unsigned short*)d_ws;      // 3.2M ushort (d-major bf16)
    unsigned short* Kb = Qb + 3200000;               // 3.2M ushort
    float*          ssum = (float*)(Kb + 3200000);   // 400,000 floats

    proj_qkv<<<(N_NODES + 31) / 32, 256, 0, stream>>>(x, Wq, bq, Wk, bk,
                                                      Wv, bv, Qb, Kb, V, ssum);

    const int nwork = N_EDGES * 8;
    edge_kernel<<<(nwork + 255) / 256, 256, 0, stream>>>(Qb, Kb, edge, prods,
                                                         ssum);
    norm_kernel<<<(nwork + 255) / 256, 256, 0, stream>>>(edge, prods, ssum,
                                                         att);
}

// Round 8
// 173.531 us; speedup vs baseline: 3.3059x; 1.0140x over previous
//
#include <hip/hip_runtime.h>
#include <hip/hip_bf16.h>
#include <hip/hip_fp16.h>

#define N_NODES 50000
#define N_EDGES 800000
// IN_F = 64, D_ATT = 64, HEADS = 8, D_HEAD = 8
// outputs: attention [E,8] | v [N,64] | prods [E,8]  (all fp32)

typedef __attribute__((ext_vector_type(4))) unsigned int uint4v;
typedef __attribute__((ext_vector_type(2))) float f32x2;   // NT-store-compatible

static __device__ __forceinline__ float bfu_lo(unsigned int u) {
    union { unsigned int u; float f; } v; v.u = u << 16; return v.f;
}
static __device__ __forceinline__ float bfu_hi(unsigned int u) {
    union { unsigned int u; float f; } v; v.u = u & 0xffff0000u; return v.f;
}
static __device__ __forceinline__ unsigned short f2bf(float f) {
    union { float f; unsigned int u; } v; v.f = f;
    v.u += 0x7fffu + ((v.u >> 16) & 1u);  // RNE
    return (unsigned short)(v.u >> 16);
}

// ---------------------------------------------------------------------------
// Kernel 1: fused Q/K/V projection + ssum zeroing (ssum now fp16: 200k
// dwords). R5 lesson: massive grids, no coop. R2 lesson: small live
// register arrays (K-chunk=8, ~64 VGPR, no spill).
// Q/K stored d-major bf16; V fp32 output.
// ---------------------------------------------------------------------------
__global__ __launch_bounds__(256, 2)
void proj_qkv(const float* __restrict__ x,
              const float* __restrict__ Wq, const float* __restrict__ bq,
              const float* __restrict__ Wk, const float* __restrict__ bk,
              const float* __restrict__ Wv, const float* __restrict__ bv,
              unsigned short* __restrict__ Qb, unsigned short* __restrict__ Kb,
              float* __restrict__ V, unsigned int* __restrict__ ssum_u)
{
    __shared__ float xs[32 * 64];  // 8 KB
    const int tid  = threadIdx.x;
    const int c    = tid & 63;      // output column 0..63
    const int w    = tid >> 6;      // wave id 0..3
    const int row0 = blockIdx.x * 32;
    const int nrows = min(32, N_NODES - row0);

    // ssum zeroing: N_NODES*8 halves = N_NODES*4 dwords (grid covers 400128)
    {
        const int z = blockIdx.x * 256 + tid;
        if (z < N_NODES * 4) ssum_u[z] = 0u;
    }

    // stage x tile once (coalesced float4)
    {
        const float4* xg  = (const float4*)(x + (size_t)row0 * 64);
        float4*       xs4 = (float4*)xs;
        const int nf4 = nrows * 16;
        for (int i = tid; i < nf4; i += 256) xs4[i] = xg[i];
    }
    __syncthreads();

    const int r0 = w * 8;  // this wave's 8 rows

    float accq[8], acck[8], accv[8];
    {
        const float bqc = bq[c], bkc = bk[c], bvc = bv[c];
#pragma unroll
        for (int i = 0; i < 8; ++i) { accq[i] = bqc; acck[i] = bkc; accv[i] = bvc; }
    }

    for (int jc = 0; jc < 8; ++jc) {  // K-dim in chunks of 8
        float wq[8], wk[8], wv[8];    // 24 live W values (L2-resident re-reads)
#pragma unroll
        for (int j = 0; j < 8; ++j) {
            const int row = (jc * 8 + j) * 64 + c;
            wq[j] = Wq[row]; wk[j] = Wk[row]; wv[j] = Wv[row];
        }
#pragma unroll
        for (int i = 0; i < 8; ++i) {
            const float4* xr = (const float4*)(xs + (r0 + i) * 64 + jc * 8);
            const float4 xv0 = xr[0], xv1 = xr[1];  // wave-uniform broadcast
            accq[i] += xv0.x * wq[0] + xv0.y * wq[1] + xv0.z * wq[2] + xv0.w * wq[3]
                     + xv1.x * wq[4] + xv1.y * wq[5] + xv1.z * wq[6] + xv1.w * wq[7];
            acck[i] += xv0.x * wk[0] + xv0.y * wk[1] + xv0.z * wk[2] + xv0.w * wk[3]
                     + xv1.x * wk[4] + xv1.y * wk[5] + xv1.z * wk[6] + xv1.w * wk[7];
            accv[i] += xv0.x * wv[0] + xv0.y * wv[1] + xv0.z * wv[2] + xv0.w * wv[3]
                     + xv1.x * wv[4] + xv1.y * wv[5] + xv1.z * wv[6] + xv1.w * wv[7];
        }
    }

    // d-major permutation for Q/K (within the 128B row segment) -> coalesced
    const int ocqk = (c & 7) * 8 + (c >> 3);
#pragma unroll
    for (int i = 0; i < 8; ++i) {
        const int r = r0 + i;
        if (r < nrows) {
            const size_t o = (size_t)(row0 + r) * 64;
            Qb[o + ocqk] = f2bf(accq[i]);
            Kb[o + ocqk] = f2bf(acck[i]);
            __builtin_nontemporal_store(accv[i], V + o + c);
        }
    }
}

// ---------------------------------------------------------------------------
// Kernel 2: 4 threads per edge, each handles a d-pair (2dp, 2dp+1).
// R6 analysis: edge kernel is atomic-op-throughput bound (~6.4M fp32 atomics
// ≈ 40 µs ≈ observed 45.5). Packed v2f16 atomic halves the op count.
// Gather coalescing preserved: lanes 0-3 read one 128 B d-major row.
// Softmax max-shift skipped: |p| <= ~8, exp() safe in fp32; ratio identical.
// ---------------------------------------------------------------------------
__global__ __launch_bounds__(256)
void edge_kernel(const unsigned short* __restrict__ Qb,
                 const unsigned short* __restrict__ Kb,
                 const int* __restrict__ edge,
                 float* __restrict__ prods, __half2* __restrict__ ssum)
{
    const int gid = blockIdx.x * 256 + threadIdx.x;
    if (gid >= N_EDGES * 4) return;
    const int e  = gid >> 2;
    const int dp = gid & 3;            // d pair index: d = 2dp, 2dp+1
    const int e0 = edge[e];            // source node (q)
    const int e1 = edge[N_EDGES + e];  // destination node (k, segment id)

    const uint4v* qr = (const uint4v*)(Qb + (size_t)e0 * 64 + dp * 16);
    const uint4v* kr = (const uint4v*)(Kb + (size_t)e1 * 64 + dp * 16);
    const uint4v q0 = qr[0], q1 = qr[1];
    const uint4v k0 = kr[0], k1 = kr[1];
    float s0 = 0.f, s1 = 0.f;
#pragma unroll
    for (int i = 0; i < 4; ++i) {
        s0 += bfu_lo(q0[i]) * bfu_lo(k0[i]);
        s0 += bfu_hi(q0[i]) * bfu_hi(k0[i]);
        s1 += bfu_lo(q1[i]) * bfu_lo(k1[i]);
        s1 += bfu_hi(q1[i]) * bfu_hi(k1[i]);
    }

    const float p0 = s0 * 0.35355339059327373f;  // 1/sqrt(8)
    const float p1 = s1 * 0.35355339059327373f;
    *(f32x2*)(prods + (size_t)e * 8 + dp * 2) = (f32x2){p0, p1};
    // one packed fp16 atomic for both d's (native global_atomic_pk_add_f16)
    unsafeAtomicAdd(ssum + (size_t)e1 * 4 + dp,
                    __floats2half2_rn(__expf(p0), __expf(p1)));
}

// ---------------------------------------------------------------------------
// Kernel 3: attention = exp(prods) / segment-sum, 2-wide.
// Cross-kernel visibility of ssum/prods via inter-dispatch release/acquire
// (worked R4/R6).
// ---------------------------------------------------------------------------
__global__ __launch_bounds__(256)
void norm_kernel(const int* __restrict__ edge,
                 const float* __restrict__ prods,
                 const __half2* __restrict__ ssum, float* __restrict__ att)
{
    const int gid = blockIdx.x * 256 + threadIdx.x;
    if (gid >= N_EDGES * 4) return;
    const int e  = gid >> 2;
    const int dp = gid & 3;
    const int e1 = edge[N_EDGES + e];

    const f32x2 p = *(const f32x2*)(prods + (size_t)e * 8 + dp * 2);
    const __half2 s2 = ssum[(size_t)e1 * 4 + dp];
    f32x2 r;
    r.x = __expf(p.x) / (__low2float(s2)  + 1e-16f);
    r.y = __expf(p.y) / (__high2float(s2) + 1e-16f);
    __builtin_nontemporal_store(r, (f32x2*)(att + (size_t)e * 8 + dp * 2));
}

extern "C" void kernel_launch(void* const* d_in, const int* in_sizes, int n_in,
                              void* d_out, int out_size, void* d_ws, size_t ws_size,
                              hipStream_t stream)
{
    const float* x    = (const float*)d_in[0];
    const float* Wq   = (const float*)d_in[1];
    const float* bq   = (const float*)d_in[2];
    const float* Wk   = (const float*)d_in[3];
    const float* bk   = (const float*)d_in[4];
    const float* Wv   = (const float*)d_in[5];
    const float* bv   = (const float*)d_in[6];
    const int*   edge = (const int*)d_in[7];

    float* out   = (float*)d_out;
    float* att   = out;                      // 6,400,000 floats
    float* V     = out + 6400000;            // 3,200,000 floats
    float* prods = out + 9600000;            // 6,400,000 floats

    unsigned short* Qb = (unsigned short*)d_ws;      // 3.2M ushort (d-major bf16)
    unsigned short* Kb = Qb + 3200000;               // 3.2M ushort
    __half2*        ssum = (__half2*)(Kb + 3200000); // 200,000 half2 (800 KB)

    proj_qkv<<<(N_NODES + 31) / 32, 256, 0, stream>>>(
        x, Wq, bq, Wk, bk, Wv, bv, Qb, Kb, V, (unsigned int*)ssum);

    const int nwork = N_EDGES * 4;
    edge_kernel<<<(nwork + 255) / 256, 256, 0, stream>>>(Qb, Kb, edge, prods,
                                                         ssum);
    norm_kernel<<<(nwork + 255) / 256, 256, 0, stream>>>(edge, prods, ssum,
                                                         att);
}